// Round 5
// baseline (315.278 us; speedup 1.0000x reference)
//
#include <hip/hip_runtime.h>
#include <hip/hip_bf16.h>
#include <stdint.h>

#define MDIM 4096
#define NDIM 4096
#define KDIM 4096
#define BM 128
#define BN 128
#define BK 32          // K per pipeline stage (1 MFMA k-step)
#define NTILE (KDIM / BK)   // 128 tiles

typedef __attribute__((ext_vector_type(8))) short bf16x8;      // MFMA A/B frag
typedef __attribute__((ext_vector_type(4))) float floatx4;     // MFMA C/D frag
typedef __attribute__((ext_vector_type(8))) unsigned short ushort8_t;

// fp32 -> bf16 round-to-nearest-even
__device__ __forceinline__ unsigned short f2bf(float f) {
  union { float f; uint32_t u; } v; v.f = f;
  uint32_t u = v.u;
  u += 0x7FFFu + ((u >> 16) & 1u);
  return (unsigned short)(u >> 16);
}

// 32-bit LDS byte offset of a __shared__ object (for M0)
__device__ __forceinline__ uint32_t lds_off(const void* p) {
  return (uint32_t)(uintptr_t)(__attribute__((address_space(3))) const void*)p;
}

// One tile's staging: 4 untracked global->LDS dwordx4 loads, 16B/lane.
// HW semantics: LDS dest = M0 + LANE*16 (lane 0..63 within the WAVE).
// Therefore M0 must be the PER-WAVE base (buffer base + wave*1024B) —
// R3/R4's block-uniform M0 made all 4 waves write the same 1KB (the NaN bug).
// M0 restored to -1 at the end; single asm block so no compiler DS op can
// observe a clobbered M0.
__device__ __forceinline__ void stage_tile(uint32_t ao, uint32_t bo,
                                           const unsigned short* a0,
                                           const unsigned short* a1,
                                           const unsigned short* b0,
                                           const unsigned short* b1) {
  asm volatile(
      "s_mov_b32 m0, %0\n\t"
      "global_load_lds_dwordx4 %4, off\n\t"
      "s_mov_b32 m0, %1\n\t"
      "global_load_lds_dwordx4 %5, off\n\t"
      "s_mov_b32 m0, %2\n\t"
      "global_load_lds_dwordx4 %6, off\n\t"
      "s_mov_b32 m0, %3\n\t"
      "global_load_lds_dwordx4 %7, off\n\t"
      "s_mov_b32 m0, -1"
      :: "s"(ao), "s"(ao + 4096u), "s"(bo), "s"(bo + 4096u),
         "v"(a0), "v"(a1), "v"(b0), "v"(b1)
      : "memory");
}

// ---------------- fp32 -> bf16 conversion into workspace ----------------
__global__ __launch_bounds__(256) void convert_bf16(const float* __restrict__ x,
                                                    const float* __restrict__ w,
                                                    unsigned short* __restrict__ xb,
                                                    unsigned short* __restrict__ wb) {
  const int64_t off = ((int64_t)blockIdx.x * 256 + threadIdx.x) * 8;
  float4 v0 = *(const float4*)(x + off);
  float4 v1 = *(const float4*)(x + off + 4);
  float4 u0 = *(const float4*)(w + off);
  float4 u1 = *(const float4*)(w + off + 4);
  ushort8_t a = {f2bf(v0.x), f2bf(v0.y), f2bf(v0.z), f2bf(v0.w),
                 f2bf(v1.x), f2bf(v1.y), f2bf(v1.z), f2bf(v1.w)};
  ushort8_t b = {f2bf(u0.x), f2bf(u0.y), f2bf(u0.z), f2bf(u0.w),
                 f2bf(u1.x), f2bf(u1.y), f2bf(u1.z), f2bf(u1.w)};
  *(ushort8_t*)(xb + off) = a;
  *(ushort8_t*)(wb + off) = b;
}

// ---------------- pipelined bf16 MFMA GEMM ----------------
// 3 LDS buffers x BK=32; 1 barrier per tile; stage(t+2) issued before
// compute(t) so 2 tiles (8 loads/wave) stay in flight; s_waitcnt vmcnt(4)
// waits only for the oldest tile. lgkmcnt(0) before each barrier closes the
// ds_read-vs-DMA-overwrite race (R2's __syncthreads gave this implicitly).
// LDS layout: 64 macro-rows x 128B; macro-row m packs rows {2m,2m+1};
// 16B slot kc holds chunk c = kc ^ (m&7) (c>>2 = row parity, c&3 = k-chunk).
__global__ __launch_bounds__(256, 3) void gemm_bf16(const unsigned short* __restrict__ A,
                                                    const unsigned short* __restrict__ B,
                                                    const float* __restrict__ bias,
                                                    float* __restrict__ C) {
  __shared__ __align__(16) unsigned short As[3][BM * BK];  // 3 x 8 KB
  __shared__ __align__(16) unsigned short Bs[3][BN * BK];  // 3 x 8 KB
  const int tid = threadIdx.x;
  const int bm = blockIdx.y, bn = blockIdx.x;
  const int lane = tid & 63, wave = tid >> 6;
  const int quad = lane >> 4, r16 = lane & 15;
  const int wm = (wave >> 1) * 64, wn = (wave & 1) * 64;

  // ---- staging map: thread -> (global row, k-chunk) for LDS slot tid*16 ----
  const int mr = tid >> 3;             // macro-row 0..31 within an issue
  const int kc = tid & 7;              // LDS slot
  const int c  = kc ^ (mr & 7);        // content chunk
  const int srow = 2 * mr + (c >> 2);
  const int scol = (c & 3) * 8;
  const unsigned short* ga0 = A + (int64_t)(bm * BM + srow) * KDIM + scol;
  const unsigned short* ga1 = ga0 + (int64_t)64 * KDIM;
  const unsigned short* gb0 = B + (int64_t)(bn * BN + srow) * KDIM + scol;
  const unsigned short* gb1 = gb0 + (int64_t)64 * KDIM;

  // per-wave LDS staging bases (SGPR-uniform): buffer base + wave*1024B
  const uint32_t wb16 = (uint32_t)__builtin_amdgcn_readfirstlane(tid >> 6) * 1024u;
  uint32_t aow[3], bow[3];
#pragma unroll
  for (int b = 0; b < 3; ++b) {
    aow[b] = lds_off(&As[b][0]) + wb16;
    bow[b] = lds_off(&Bs[b][0]) + wb16;
  }

  // ---- compute-side LDS indices (shorts), one per fragment row ----
  int ia[4], ib[4];
#pragma unroll
  for (int i = 0; i < 4; ++i) {
    const int ra = wm + i * 16 + r16;
    ia[i] = (ra >> 1) * 64 + (((((ra & 1) << 2) | quad) ^ ((ra >> 1) & 7))) * 8;
    const int rb = wn + i * 16 + r16;
    ib[i] = (rb >> 1) * 64 + (((((rb & 1) << 2) | quad) ^ ((rb >> 1) & 7))) * 8;
  }

  floatx4 acc[4][4] = {};

#define STAGE(T, AO, BO) \
    stage_tile((AO), (BO), ga0 + (int64_t)(T) * BK, ga1 + (int64_t)(T) * BK, \
               gb0 + (int64_t)(T) * BK, gb1 + (int64_t)(T) * BK)

#define COMPUTE(BUF) do {                                       \
    bf16x8 af[4], bg[4];                                        \
    _Pragma("unroll")                                           \
    for (int i = 0; i < 4; ++i) af[i] = *(const bf16x8*)(&As[BUF][ia[i]]); \
    _Pragma("unroll")                                           \
    for (int i = 0; i < 4; ++i) bg[i] = *(const bf16x8*)(&Bs[BUF][ib[i]]); \
    _Pragma("unroll")                                           \
    for (int i = 0; i < 4; ++i)                                 \
      _Pragma("unroll")                                         \
      for (int j = 0; j < 4; ++j)                               \
        acc[i][j] = __builtin_amdgcn_mfma_f32_16x16x32_bf16(af[i], bg[j], acc[i][j], 0, 0, 0); \
  } while (0)

  // prologue: clean vmcnt baseline, then stage tiles 0,1
  asm volatile("s_waitcnt vmcnt(0)" ::: "memory");
  STAGE(0, aow[0], bow[0]);
  STAGE(1, aow[1], bow[1]);

  int t = 0;
#pragma unroll 1
  for (int it = 0; it < (NTILE - 2) / 3; ++it) {   // 42 triples -> computes tiles 0..125
    asm volatile("s_waitcnt vmcnt(4) lgkmcnt(0)" ::: "memory");
    asm volatile("s_barrier" ::: "memory");
    STAGE(t + 2, aow[2], bow[2]);
    COMPUTE(0);

    asm volatile("s_waitcnt vmcnt(4) lgkmcnt(0)" ::: "memory");
    asm volatile("s_barrier" ::: "memory");
    STAGE(t + 3, aow[0], bow[0]);
    COMPUTE(1);

    asm volatile("s_waitcnt vmcnt(4) lgkmcnt(0)" ::: "memory");
    asm volatile("s_barrier" ::: "memory");
    STAGE(t + 4, aow[1], bow[1]);
    COMPUTE(2);

    t += 3;
  }
  // peeled tail: tiles 126 (buf0) and 127 (buf1), nothing left to stage
  asm volatile("s_waitcnt vmcnt(4) lgkmcnt(0)" ::: "memory");
  asm volatile("s_barrier" ::: "memory");
  COMPUTE(0);
  asm volatile("s_waitcnt vmcnt(0) lgkmcnt(0)" ::: "memory");
  asm volatile("s_barrier" ::: "memory");
  COMPUTE(1);

#undef STAGE
#undef COMPUTE

  // epilogue: C/D layout col = lane&15, row = quad*4 + r (m89-verified)
  const int col0 = bn * BN + wn + r16;
  const int row0 = bm * BM + wm + quad * 4;
#pragma unroll
  for (int j = 0; j < 4; ++j) {
    const float bv = bias[col0 + j * 16];
#pragma unroll
    for (int i = 0; i < 4; ++i) {
      float* cp = C + (int64_t)(row0 + i * 16) * NDIM + col0 + j * 16;
#pragma unroll
      for (int r = 0; r < 4; ++r)
        cp[(int64_t)r * NDIM] = acc[i][j][r] + bv;
    }
  }
}

// ---------------- fallback: fp32 inputs, convert in staging (no workspace) ----------------
#define FBK 32
__global__ __launch_bounds__(256) void gemm_f32in(const float* __restrict__ A,
                                                  const float* __restrict__ W,
                                                  const float* __restrict__ bias,
                                                  float* __restrict__ C) {
  __shared__ __align__(16) unsigned short As[BM * FBK];
  __shared__ __align__(16) unsigned short Bs[BN * FBK];
  const int tid = threadIdx.x;
  const int bm = blockIdx.y, bn = blockIdx.x;
  const int lane = tid & 63, wave = tid >> 6;
  const int quad = lane >> 4, r16 = lane & 15;
  const int wm = (wave >> 1) * 64, wn = (wave & 1) * 64;

  const int srow = tid >> 1;
  const int scol = (tid & 1) * 16;
  const float* ag = A + (int64_t)(bm * BM + srow) * KDIM + scol;
  const float* bg = W + (int64_t)(bn * BN + srow) * KDIM + scol;
  unsigned short* al = As + srow * FBK + scol;
  unsigned short* bl = Bs + srow * FBK + scol;

  floatx4 acc[4][4] = {};
  for (int k0 = 0; k0 < KDIM; k0 += FBK) {
    float4 a0 = *(const float4*)(ag + k0);
    float4 a1 = *(const float4*)(ag + k0 + 4);
    float4 a2 = *(const float4*)(ag + k0 + 8);
    float4 a3 = *(const float4*)(ag + k0 + 12);
    float4 b0 = *(const float4*)(bg + k0);
    float4 b1 = *(const float4*)(bg + k0 + 4);
    float4 b2 = *(const float4*)(bg + k0 + 8);
    float4 b3 = *(const float4*)(bg + k0 + 12);
    ushort8_t pa0 = {f2bf(a0.x), f2bf(a0.y), f2bf(a0.z), f2bf(a0.w),
                     f2bf(a1.x), f2bf(a1.y), f2bf(a1.z), f2bf(a1.w)};
    ushort8_t pa1 = {f2bf(a2.x), f2bf(a2.y), f2bf(a2.z), f2bf(a2.w),
                     f2bf(a3.x), f2bf(a3.y), f2bf(a3.z), f2bf(a3.w)};
    ushort8_t pb0 = {f2bf(b0.x), f2bf(b0.y), f2bf(b0.z), f2bf(b0.w),
                     f2bf(b1.x), f2bf(b1.y), f2bf(b1.z), f2bf(b1.w)};
    ushort8_t pb1 = {f2bf(b2.x), f2bf(b2.y), f2bf(b2.z), f2bf(b2.w),
                     f2bf(b3.x), f2bf(b3.y), f2bf(b3.z), f2bf(b3.w)};
    *(ushort8_t*)al = pa0;
    *(ushort8_t*)(al + 8) = pa1;
    *(ushort8_t*)bl = pb0;
    *(ushort8_t*)(bl + 8) = pb1;
    __syncthreads();

    bf16x8 a[4], b[4];
#pragma unroll
    for (int i = 0; i < 4; ++i)
      a[i] = *(const bf16x8*)(As + (wm + i * 16 + r16) * FBK + quad * 8);
#pragma unroll
    for (int i = 0; i < 4; ++i)
      b[i] = *(const bf16x8*)(Bs + (wn + i * 16 + r16) * FBK + quad * 8);
#pragma unroll
    for (int i = 0; i < 4; ++i)
#pragma unroll
      for (int j = 0; j < 4; ++j)
        acc[i][j] = __builtin_amdgcn_mfma_f32_16x16x32_bf16(a[i], b[j], acc[i][j], 0, 0, 0);
    __syncthreads();
  }

  const int col0 = bn * BN + wn + r16;
  const int row0 = bm * BM + wm + quad * 4;
#pragma unroll
  for (int j = 0; j < 4; ++j) {
    const float bv = bias[col0 + j * 16];
#pragma unroll
    for (int i = 0; i < 4; ++i) {
      float* cp = C + (int64_t)(row0 + i * 16) * NDIM + col0 + j * 16;
#pragma unroll
      for (int r = 0; r < 4; ++r)
        cp[(int64_t)r * NDIM] = acc[i][j][r] + bv;
    }
  }
}

extern "C" void kernel_launch(void* const* d_in, const int* in_sizes, int n_in,
                              void* d_out, int out_size, void* d_ws, size_t ws_size,
                              hipStream_t stream) {
  const float* x    = (const float*)d_in[0];   // [4096, 4096]
  const float* w    = (const float*)d_in[1];   // [4096, 4096]
  const float* bias = (const float*)d_in[2];   // [4096]
  float* out = (float*)d_out;

  dim3 grid(NDIM / BN, MDIM / BM);  // 32 x 32 = 1024 blocks
  const size_t need = (size_t)2 * MDIM * KDIM * sizeof(unsigned short);  // 64 MB
  if (ws_size >= need) {
    unsigned short* xb = (unsigned short*)d_ws;
    unsigned short* wb = xb + (size_t)MDIM * KDIM;
    convert_bf16<<<8192, 256, 0, stream>>>(x, w, xb, wb);
    gemm_bf16<<<grid, 256, 0, stream>>>(xb, wb, bias, out);
  } else {
    gemm_f32in<<<grid, 256, 0, stream>>>(x, w, bias, out);
  }
}